// Round 1
// baseline (225.569 us; speedup 1.0000x reference)
//
#include <hip/hip_runtime.h>
#include <hip/hip_bf16.h>
#include <stdint.h>

// B=8, N=1024, D=1024.  out = relu(adj @ (y@W) / adj_sumrow + b + x)
// Strategy: bf16 MFMA for both 1024^3 x8 GEMMs (threshold 1.02e-1 tolerates it;
// GEMM2's error is divided by rowsum~512). m97-style 128x128 tile, BK=32,
// global_load_lds width=16, ds_read_b128 fragments, fused epilogue in GEMM2.

typedef float  f32x4  __attribute__((ext_vector_type(4)));
typedef __bf16 bf16x8 __attribute__((ext_vector_type(8)));

__device__ __forceinline__ unsigned short f2bf(float f) {
  union { float f; unsigned int u; } c; c.f = f;
  unsigned int u = c.u;
  u += 0x7FFFu + ((u >> 16) & 1u);   // RNE; inputs are finite
  return (unsigned short)(u >> 16);
}

__device__ __forceinline__ void async_cp16(const void* g, void* l) {
  __builtin_amdgcn_global_load_lds(
      (const __attribute__((address_space(1))) unsigned int*)g,
      (__attribute__((address_space(3))) unsigned int*)l, 16, 0, 0);
}

// ---------------- pre-pass kernels ----------------

__global__ void k_cvt(const float4* __restrict__ src, ushort4* __restrict__ dst, int n4) {
  int i = blockIdx.x * blockDim.x + threadIdx.x;
  if (i >= n4) return;
  float4 v = src[i];
  ushort4 p;
  p.x = f2bf(v.x); p.y = f2bf(v.y); p.z = f2bf(v.z); p.w = f2bf(v.w);
  dst[i] = p;
}

// Wt[n][k] = W[k][n], f32 -> bf16, 64x64 LDS tiles
__global__ void k_transpose_cvt(const float* __restrict__ W, unsigned short* __restrict__ Wt) {
  __shared__ float t[64][65];
  const int tx = threadIdx.x, ty = threadIdx.y;
  const int n0 = blockIdx.x * 64, k0 = blockIdx.y * 64;
#pragma unroll
  for (int r = ty; r < 64; r += 4)
    t[r][tx] = W[(size_t)(k0 + r) * 1024 + n0 + tx];
  __syncthreads();
#pragma unroll
  for (int r = ty; r < 64; r += 4)
    Wt[(size_t)(n0 + r) * 1024 + k0 + tx] = f2bf(t[tx][r]);
}

// ---------------- GEMM mainloop (shared) ----------------
// A  : [1024][1024] bf16 row-major, tile rows = m
// Bt : [1024][1024] bf16 row-major = B^T, tile rows = n
// 128x128 block tile, BK=32, 4 waves each computing 64x64 (4x4 of 16x16x32 MFMA)

__device__ __forceinline__ void gemm_mainloop(
    const unsigned short* __restrict__ A,
    const unsigned short* __restrict__ Bt,
    int m0, int n0, f32x4 acc[4][4],
    unsigned short* lA, unsigned short* lB, int tid)
{
  const int lane = tid & 63;
  const int wave = tid >> 6;
  const int wm   = (wave >> 1) * 64;
  const int wn   = (wave & 1) * 64;
  const int quad = lane >> 4;
  const int l16  = lane & 15;
  const int srow = lane >> 2;        // 0..15 within a 16-row chunk
  const int scol = (lane & 3) * 8;   // k element offset (16B per lane)

#pragma unroll 1
  for (int k0 = 0; k0 < 1024; k0 += 32) {
    // stage: 8 chunks of 16 rows x 32 bf16 (1024B) per matrix; 2 chunks/wave
#pragma unroll
    for (int s = 0; s < 2; ++s) {
      const int c = wave * 2 + s;    // 0..7, wave-uniform
      async_cp16(A  + (((size_t)(m0 + c * 16 + srow)) << 10) + k0 + scol, lA + c * 512);
      async_cp16(Bt + (((size_t)(n0 + c * 16 + srow)) << 10) + k0 + scol, lB + c * 512);
    }
    __syncthreads();   // drains vmcnt(0): global_load_lds complete

    bf16x8 af[4], bfr[4];
#pragma unroll
    for (int i = 0; i < 4; ++i)
      af[i]  = *(const bf16x8*)(lA + (wm + i * 16 + l16) * 32 + quad * 8);
#pragma unroll
    for (int j = 0; j < 4; ++j)
      bfr[j] = *(const bf16x8*)(lB + (wn + j * 16 + l16) * 32 + quad * 8);

#pragma unroll
    for (int i = 0; i < 4; ++i)
#pragma unroll
      for (int j = 0; j < 4; ++j)
        acc[i][j] = __builtin_amdgcn_mfma_f32_16x16x32_bf16(af[i], bfr[j], acc[i][j], 0, 0, 0);
    __syncthreads();   // protect LDS before next stage
  }
}

// ---------------- GEMM1: support^T = (y @ W)^T, bf16 out ----------------

__global__ __launch_bounds__(256) void k_gemm1(
    const unsigned short* __restrict__ Ybf,   // [8][1024][1024]
    const unsigned short* __restrict__ Wt,    // [1024][1024] = W^T
    unsigned short* __restrict__ SupT)        // [8][1024][1024] : SupT[b][d][n]
{
  __shared__ __align__(16) unsigned short lA[128 * 32];
  __shared__ __align__(16) unsigned short lB[128 * 32];
  const int tid = threadIdx.x;
  const int n0 = blockIdx.x * 128, m0 = blockIdx.y * 128, b = blockIdx.z;

  f32x4 acc[4][4];
#pragma unroll
  for (int i = 0; i < 4; ++i)
#pragma unroll
    for (int j = 0; j < 4; ++j)
#pragma unroll
      for (int r = 0; r < 4; ++r) acc[i][j][r] = 0.0f;

  gemm_mainloop(Ybf + ((size_t)b << 20), Wt, m0, n0, acc, lA, lB, tid);

  unsigned short* Sb = SupT + ((size_t)b << 20);
  const int lane = tid & 63, wave = tid >> 6;
  const int wm = (wave >> 1) * 64, wn = (wave & 1) * 64;
  const int quad = lane >> 4, l16 = lane & 15;
  // C/D layout: col = lane&15, row = quad*4+reg -> 4 consecutive rows at one col
  // transposed store: SupT[n][m..m+3] is 4 consecutive bf16 = one 8B store
#pragma unroll
  for (int i = 0; i < 4; ++i) {
    const int mb = m0 + wm + i * 16 + quad * 4;
#pragma unroll
    for (int j = 0; j < 4; ++j) {
      const int n = n0 + wn + j * 16 + l16;
      ushort4 p;
      p.x = f2bf(acc[i][j][0]); p.y = f2bf(acc[i][j][1]);
      p.z = f2bf(acc[i][j][2]); p.w = f2bf(acc[i][j][3]);
      *(ushort4*)(Sb + (((size_t)n) << 10) + mb) = p;
    }
  }
}

// ---------------- GEMM2: out = relu(adj@support / rowsum + bias + x), f32 out --------

__global__ __launch_bounds__(256) void k_gemm2(
    const unsigned short* __restrict__ AdjBf, // [8][1024][1024]
    const unsigned short* __restrict__ SupT,  // [8][1024][1024] (B^T layout)
    const float* __restrict__ x,              // [8][1024][1024]
    const float* __restrict__ sumrow,         // [8][1024]
    const float* __restrict__ bias,           // [1024]
    float* __restrict__ out)                  // [8][1024][1024]
{
  __shared__ __align__(16) unsigned short lA[128 * 32];
  __shared__ __align__(16) unsigned short lB[128 * 32];
  const int tid = threadIdx.x;
  const int n0 = blockIdx.x * 128, m0 = blockIdx.y * 128, b = blockIdx.z;

  f32x4 acc[4][4];
#pragma unroll
  for (int i = 0; i < 4; ++i)
#pragma unroll
    for (int j = 0; j < 4; ++j)
#pragma unroll
      for (int r = 0; r < 4; ++r) acc[i][j][r] = 0.0f;

  gemm_mainloop(AdjBf + ((size_t)b << 20), SupT + ((size_t)b << 20), m0, n0, acc, lA, lB, tid);

  const float* xb = x   + ((size_t)b << 20);
  float*       ob = out + ((size_t)b << 20);
  const float* sr = sumrow + ((size_t)b << 10);
  const int lane = tid & 63, wave = tid >> 6;
  const int wm = (wave >> 1) * 64, wn = (wave & 1) * 64;
  const int quad = lane >> 4, l16 = lane & 15;

  float bv[4];
#pragma unroll
  for (int j = 0; j < 4; ++j) bv[j] = bias[n0 + wn + j * 16 + l16];

#pragma unroll
  for (int i = 0; i < 4; ++i) {
    const int mb = m0 + wm + i * 16 + quad * 4;
#pragma unroll
    for (int r = 0; r < 4; ++r) {
      const int m = mb + r;
      const float inv = 1.0f / sr[m];
#pragma unroll
      for (int j = 0; j < 4; ++j) {
        const int n = n0 + wn + j * 16 + l16;
        const size_t idx = (((size_t)m) << 10) + n;
        float v = acc[i][j][r] * inv + bv[j] + xb[idx];
        ob[idx] = fmaxf(v, 0.0f);
      }
    }
  }
}

// ---------------- launcher ----------------

extern "C" void kernel_launch(void* const* d_in, const int* in_sizes, int n_in,
                              void* d_out, int out_size, void* d_ws, size_t ws_size,
                              hipStream_t stream) {
  const float* x      = (const float*)d_in[0];  // [8][1024][1024]
  const float* y      = (const float*)d_in[1];  // [8][1024][1024]
  const float* adj    = (const float*)d_in[2];  // [8][1024][1024]
  const float* sumrow = (const float*)d_in[3];  // [8][1024][1]
  const float* W      = (const float*)d_in[4];  // [1024][1024]
  const float* bias   = (const float*)d_in[5];  // [1024]
  float* out = (float*)d_out;

  char* ws = (char*)d_ws;
  unsigned short* ybf   = (unsigned short*)(ws);                       // 16 MB
  unsigned short* adjbf = (unsigned short*)(ws + ((size_t)16 << 20));  // 16 MB
  unsigned short* wt    = (unsigned short*)(ws + ((size_t)32 << 20));  //  2 MB
  unsigned short* supT  = (unsigned short*)(ws + ((size_t)34 << 20));  // 16 MB

  const int n4 = (8 << 20) / 4;  // 2M float4 groups per 8M-element tensor
  k_cvt<<<dim3(n4 / 256), dim3(256), 0, stream>>>((const float4*)y,   (ushort4*)ybf,   n4);
  k_cvt<<<dim3(n4 / 256), dim3(256), 0, stream>>>((const float4*)adj, (ushort4*)adjbf, n4);
  k_transpose_cvt<<<dim3(16, 16), dim3(64, 4), 0, stream>>>(W, wt);
  k_gemm1<<<dim3(8, 8, 8), dim3(256), 0, stream>>>(ybf, wt, supT);
  k_gemm2<<<dim3(8, 8, 8), dim3(256), 0, stream>>>(adjbf, supT, x, sumrow, bias, out);
}

// Round 2
// 207.085 us; speedup vs baseline: 1.0893x; 1.0893x over previous
//
#include <hip/hip_runtime.h>
#include <hip/hip_bf16.h>
#include <stdint.h>

// B=8, N=1024, D=1024.  out = relu(adj @ (y@W) / adj_sumrow + b + x)
// bf16 MFMA for both GEMM passes. R2: BK=64, XOR-swizzled LDS (conflict-free
// ds_read_b128), GEMM1 recast as SupT = Wt @ Y^T (batched N=8192, no
// scattered stores, Wt L2-resident).

typedef float  f32x4  __attribute__((ext_vector_type(4)));
typedef __bf16 bf16x8 __attribute__((ext_vector_type(8)));

__device__ __forceinline__ unsigned short f2bf(float f) {
  union { float f; unsigned int u; } c; c.f = f;
  unsigned int u = c.u;
  u += 0x7FFFu + ((u >> 16) & 1u);   // RNE; inputs finite
  return (unsigned short)(u >> 16);
}

__device__ __forceinline__ void async_cp16(const void* g, void* l) {
  __builtin_amdgcn_global_load_lds(
      (const __attribute__((address_space(1))) unsigned int*)g,
      (__attribute__((address_space(3))) unsigned int*)l, 16, 0, 0);
}

// ---------------- pre-pass kernels ----------------

__global__ void k_cvt(const float4* __restrict__ src, ushort4* __restrict__ dst, int n4) {
  int i = blockIdx.x * blockDim.x + threadIdx.x;
  if (i >= n4) return;
  float4 v = src[i];
  ushort4 p;
  p.x = f2bf(v.x); p.y = f2bf(v.y); p.z = f2bf(v.z); p.w = f2bf(v.w);
  dst[i] = p;
}

// Wt[n][k] = W[k][n], f32 -> bf16
__global__ void k_transpose_cvt(const float* __restrict__ W, unsigned short* __restrict__ Wt) {
  __shared__ float t[64][65];
  const int tx = threadIdx.x, ty = threadIdx.y;
  const int n0 = blockIdx.x * 64, k0 = blockIdx.y * 64;
#pragma unroll
  for (int r = ty; r < 64; r += 4)
    t[r][tx] = W[(size_t)(k0 + r) * 1024 + n0 + tx];
  __syncthreads();
#pragma unroll
  for (int r = ty; r < 64; r += 4)
    Wt[(size_t)(n0 + r) * 1024 + k0 + tx] = f2bf(t[tx][r]);
}

// ---------------- GEMM mainloop (shared), BK=64, swizzled LDS ----------------
// A  [M][K] bf16 row-major (stride strideA), tile rows = m
// Bt [N][K] bf16 row-major (stride strideB), tile rows = n
// 128x128 block tile, 4 waves (2x2), each wave 64x64 via 4x4 of 16x16x32 MFMA.
// LDS row = 128B = 8 chunks of 16B; physical chunk p = (logical c + row) & 7.
// Staging applies the inverse permutation on the *global* column, so the
// wave-linear global_load_lds destination lands each chunk at its swizzled slot.

__device__ __forceinline__ void gemm_mainloop64(
    const unsigned short* __restrict__ A,  int strideA,
    const unsigned short* __restrict__ Bt, int strideB,
    int m0, int n0, f32x4 acc[4][4],
    unsigned short* lA, unsigned short* lB, int tid)
{
  const int lane = tid & 63;
  const int wave = tid >> 6;
  const int wm   = (wave >> 1) * 64;
  const int wn   = (wave & 1) * 64;
  const int quad = lane >> 4;
  const int l16  = lane & 15;
  const int rg   = lane >> 3;                      // row within 8-row granule
  const int colo = (((lane & 7) - rg) & 7) * 8;    // swizzled k-offset (elements)

#pragma unroll 1
  for (int k0 = 0; k0 < 1024; k0 += 64) {
    // stage 128 rows x 64 cols per matrix: 16 granules of 8 rows, 4/wave
#pragma unroll
    for (int s = 0; s < 4; ++s) {
      const int t = wave * 4 + s;                  // wave-uniform granule id
      async_cp16(A  + (size_t)(m0 + t * 8 + rg) * strideA + k0 + colo, lA + t * 512);
      async_cp16(Bt + (size_t)(n0 + t * 8 + rg) * strideB + k0 + colo, lB + t * 512);
    }
    __syncthreads();   // drains vmcnt(0)

#pragma unroll
    for (int h = 0; h < 2; ++h) {                  // two k-halves of 32
      bf16x8 af[4], bfr[4];
#pragma unroll
      for (int i = 0; i < 4; ++i) {
        const int r = wm + i * 16 + l16;
        af[i]  = *(const bf16x8*)(lA + r * 64 + ((h * 4 + quad + r) & 7) * 8);
      }
#pragma unroll
      for (int j = 0; j < 4; ++j) {
        const int r = wn + j * 16 + l16;
        bfr[j] = *(const bf16x8*)(lB + r * 64 + ((h * 4 + quad + r) & 7) * 8);
      }
#pragma unroll
      for (int i = 0; i < 4; ++i)
#pragma unroll
        for (int j = 0; j < 4; ++j)
          acc[i][j] = __builtin_amdgcn_mfma_f32_16x16x32_bf16(af[i], bfr[j], acc[i][j], 0, 0, 0);
    }
    __syncthreads();
  }
}

__device__ __forceinline__ void zero_acc(f32x4 acc[4][4]) {
#pragma unroll
  for (int i = 0; i < 4; ++i)
#pragma unroll
    for (int j = 0; j < 4; ++j)
#pragma unroll
      for (int r = 0; r < 4; ++r) acc[i][j][r] = 0.0f;
}

// ---------------- GEMM1: Sup2[d][b*1024+n] = (y@W)^T, bf16 out ----------------
// C = Wt @ Y^T : A = Wt [1024][1024], Bt = Ybf viewed [8192][1024].

__global__ __launch_bounds__(256) void k_gemm1(
    const unsigned short* __restrict__ Wt,    // [1024][1024]
    const unsigned short* __restrict__ Ybf,   // [8192][1024]
    unsigned short* __restrict__ Sup2)        // [1024][8192]
{
  __shared__ __align__(16) unsigned short lA[128 * 64];
  __shared__ __align__(16) unsigned short lB[128 * 64];
  const int tid = threadIdx.x;
  const int n0 = blockIdx.x * 128, m0 = blockIdx.y * 128;

  f32x4 acc[4][4];
  zero_acc(acc);
  gemm_mainloop64(Wt, 1024, Ybf, 1024, m0, n0, acc, lA, lB, tid);

  const int lane = tid & 63, wave = tid >> 6;
  const int wm = (wave >> 1) * 64, wn = (wave & 1) * 64;
  const int quad = lane >> 4, l16 = lane & 15;
  // C/D: col = lane&15, row = quad*4 + reg. Row-major store, n contiguous.
#pragma unroll
  for (int i = 0; i < 4; ++i) {
    const int mb = m0 + wm + i * 16 + quad * 4;
#pragma unroll
    for (int r = 0; r < 4; ++r) {
      unsigned short* row = Sup2 + ((size_t)(mb + r) << 13);  // *8192
#pragma unroll
      for (int j = 0; j < 4; ++j)
        row[n0 + wn + j * 16 + l16] = f2bf(acc[i][j][r]);
    }
  }
}

// ------- GEMM2: out = relu(adj@support / rowsum + bias + x), f32 out -------

__global__ __launch_bounds__(256) void k_gemm2(
    const unsigned short* __restrict__ AdjBf, // [8][1024][1024]
    const unsigned short* __restrict__ Sup2,  // [1024][8192]; Bt row n = Sup2+n*8192+b*1024
    const float* __restrict__ x,
    const float* __restrict__ sumrow,         // [8][1024]
    const float* __restrict__ bias,           // [1024]
    float* __restrict__ out)
{
  __shared__ __align__(16) unsigned short lA[128 * 64];
  __shared__ __align__(16) unsigned short lB[128 * 64];
  const int tid = threadIdx.x;
  const int n0 = blockIdx.x * 128, m0 = blockIdx.y * 128, b = blockIdx.z;

  f32x4 acc[4][4];
  zero_acc(acc);
  gemm_mainloop64(AdjBf + ((size_t)b << 20), 1024,
                  Sup2 + ((size_t)b << 10), 8192,
                  m0, n0, acc, lA, lB, tid);

  const float* xb = x   + ((size_t)b << 20);
  float*       ob = out + ((size_t)b << 20);
  const float* sr = sumrow + ((size_t)b << 10);
  const int lane = tid & 63, wave = tid >> 6;
  const int wm = (wave >> 1) * 64, wn = (wave & 1) * 64;
  const int quad = lane >> 4, l16 = lane & 15;

  float bv[4];
#pragma unroll
  for (int j = 0; j < 4; ++j) bv[j] = bias[n0 + wn + j * 16 + l16];

#pragma unroll
  for (int i = 0; i < 4; ++i) {
    const int mb = m0 + wm + i * 16 + quad * 4;
#pragma unroll
    for (int r = 0; r < 4; ++r) {
      const int m = mb + r;
      const float inv = 1.0f / sr[m];
#pragma unroll
      for (int j = 0; j < 4; ++j) {
        const int n = n0 + wn + j * 16 + l16;
        const size_t idx = (((size_t)m) << 10) + n;
        float v = acc[i][j][r] * inv + bv[j] + xb[idx];
        ob[idx] = fmaxf(v, 0.0f);
      }
    }
  }
}

// ---------------- launcher ----------------

extern "C" void kernel_launch(void* const* d_in, const int* in_sizes, int n_in,
                              void* d_out, int out_size, void* d_ws, size_t ws_size,
                              hipStream_t stream) {
  const float* x      = (const float*)d_in[0];
  const float* y      = (const float*)d_in[1];
  const float* adj    = (const float*)d_in[2];
  const float* sumrow = (const float*)d_in[3];
  const float* W      = (const float*)d_in[4];
  const float* bias   = (const float*)d_in[5];
  float* out = (float*)d_out;

  char* ws = (char*)d_ws;
  unsigned short* ybf   = (unsigned short*)(ws);                       // 16 MB
  unsigned short* adjbf = (unsigned short*)(ws + ((size_t)16 << 20));  // 16 MB
  unsigned short* wt    = (unsigned short*)(ws + ((size_t)32 << 20));  //  2 MB
  unsigned short* sup2  = (unsigned short*)(ws + ((size_t)34 << 20));  // 16 MB

  const int n4 = (8 << 20) / 4;
  k_cvt<<<dim3(n4 / 256), dim3(256), 0, stream>>>((const float4*)y,   (ushort4*)ybf,   n4);
  k_cvt<<<dim3(n4 / 256), dim3(256), 0, stream>>>((const float4*)adj, (ushort4*)adjbf, n4);
  k_transpose_cvt<<<dim3(16, 16), dim3(64, 4), 0, stream>>>(W, wt);
  k_gemm1<<<dim3(64, 8), dim3(256), 0, stream>>>(wt, ybf, sup2);
  k_gemm2<<<dim3(8, 8, 8), dim3(256), 0, stream>>>(adjbf, sup2, x, sumrow, bias, out);
}

// Round 3
// 197.049 us; speedup vs baseline: 1.1447x; 1.0509x over previous
//
#include <hip/hip_runtime.h>
#include <hip/hip_bf16.h>
#include <stdint.h>

// B=8, N=1024, D=1024.  out = relu(adj @ (y@W) / adj_sumrow + b + x)
// R3: double-buffered LDS pipeline with raw s_barrier + s_waitcnt vmcnt(8)
// (loads stay in flight across barriers); single fused pre-pass kernel.

typedef float  f32x4  __attribute__((ext_vector_type(4)));
typedef __bf16 bf16x8 __attribute__((ext_vector_type(8)));

__device__ __forceinline__ unsigned short f2bf(float f) {
  union { float f; unsigned int u; } c; c.f = f;
  unsigned int u = c.u;
  u += 0x7FFFu + ((u >> 16) & 1u);   // RNE; inputs finite
  return (unsigned short)(u >> 16);
}

__device__ __forceinline__ void async_cp16(const void* g, void* l) {
  __builtin_amdgcn_global_load_lds(
      (const __attribute__((address_space(1))) unsigned int*)g,
      (__attribute__((address_space(3))) unsigned int*)l, 16, 0, 0);
}

__device__ __forceinline__ void bar() { asm volatile("s_barrier" ::: "memory"); }

// ---------------- fused pre-pass ----------------
// blocks [0,16384): y/adj f32->bf16 (float4->ushort4)
// blocks [16384,16640): W transpose+cvt (64x64 tiles)

__global__ __launch_bounds__(256) void k_prep(
    const float4* __restrict__ y4, const float4* __restrict__ a4,
    ushort4* __restrict__ yb, ushort4* __restrict__ ab,
    const float* __restrict__ W, unsigned short* __restrict__ Wt)
{
  __shared__ float t[64][65];
  const int bid = blockIdx.x;
  if (bid < 16384) {
    const int i = bid * 256 + threadIdx.x;
    const bool isY = i < 2097152;
    const float4 v = isY ? y4[i] : a4[i - 2097152];
    ushort4 p;
    p.x = f2bf(v.x); p.y = f2bf(v.y); p.z = f2bf(v.z); p.w = f2bf(v.w);
    if (isY) yb[i] = p; else ab[i - 2097152] = p;
  } else {
    const int id = bid - 16384;
    const int n0 = (id & 15) * 64, k0 = (id >> 4) * 64;
    const int tx = threadIdx.x & 63, ty = threadIdx.x >> 6;
#pragma unroll
    for (int r = ty; r < 64; r += 4)
      t[r][tx] = W[(size_t)(k0 + r) * 1024 + n0 + tx];
    __syncthreads();
#pragma unroll
    for (int r = ty; r < 64; r += 4)
      Wt[(size_t)(n0 + r) * 1024 + k0 + tx] = f2bf(t[tx][r]);
  }
}

// ---------------- GEMM pieces: 128x128 tile, BK=64, swizzled LDS ----------------
// LDS row = 128B = 8 chunks of 16B; physical chunk = (logical + row) & 7.
// Staging applies inverse permutation on the global column (free).

__device__ __forceinline__ void stage64(
    const unsigned short* __restrict__ A,  int sA,
    const unsigned short* __restrict__ Bt, int sB,
    int m0, int n0, int k0,
    unsigned short* la, unsigned short* lb,
    int wave, int rg, int colo)
{
#pragma unroll
  for (int s = 0; s < 4; ++s) {
    const int t = wave * 4 + s;                  // wave-uniform granule id
    async_cp16(A  + (size_t)(m0 + t * 8 + rg) * sA + k0 + colo, la + t * 512);
    async_cp16(Bt + (size_t)(n0 + t * 8 + rg) * sB + k0 + colo, lb + t * 512);
  }
}

__device__ __forceinline__ void compute64(
    const unsigned short* la, const unsigned short* lb,
    f32x4 acc[4][4], int wm, int wn, int quad, int l16)
{
#pragma unroll
  for (int h = 0; h < 2; ++h) {
    bf16x8 af[4], bfr[4];
#pragma unroll
    for (int i = 0; i < 4; ++i) {
      const int r = wm + i * 16 + l16;
      af[i] = *(const bf16x8*)(la + r * 64 + ((h * 4 + quad + r) & 7) * 8);
    }
#pragma unroll
    for (int j = 0; j < 4; ++j) {
      const int r = wn + j * 16 + l16;
      bfr[j] = *(const bf16x8*)(lb + r * 64 + ((h * 4 + quad + r) & 7) * 8);
    }
#pragma unroll
    for (int i = 0; i < 4; ++i)
#pragma unroll
      for (int j = 0; j < 4; ++j)
        acc[i][j] = __builtin_amdgcn_mfma_f32_16x16x32_bf16(af[i], bfr[j], acc[i][j], 0, 0, 0);
  }
}

// Double-buffered mainloop: per stage each wave issues 8 global_load_lds.
// issue(next) -> vmcnt(8) waits prev stage only -> barrier -> compute -> barrier.
__device__ __forceinline__ void gemm_dbuf(
    const unsigned short* __restrict__ A,  int sA,
    const unsigned short* __restrict__ Bt, int sB,
    int m0, int n0, f32x4 acc[4][4], unsigned short* lsm, int tid)
{
  const int lane = tid & 63, wave = tid >> 6;
  const int wm = (wave >> 1) * 64, wn = (wave & 1) * 64;
  const int quad = lane >> 4, l16 = lane & 15;
  const int rg = lane >> 3;
  const int colo = (((lane & 7) - rg) & 7) * 8;    // inverse-swizzled k-offset
  unsigned short* la0 = lsm;
  unsigned short* lb0 = lsm + 8192;
  unsigned short* la1 = lsm + 16384;
  unsigned short* lb1 = lsm + 24576;

  stage64(A, sA, Bt, sB, m0, n0, 0, la0, lb0, wave, rg, colo);
#pragma unroll 1
  for (int k0 = 0; k0 < 1024; k0 += 128) {
    // stage A: compute buf0 @ k0, prefetch k0+64 into buf1
    stage64(A, sA, Bt, sB, m0, n0, k0 + 64, la1, lb1, wave, rg, colo);
    asm volatile("s_waitcnt vmcnt(8)" ::: "memory");
    bar();
    compute64(la0, lb0, acc, wm, wn, quad, l16);
    bar();
    // stage B: compute buf1 @ k0+64, prefetch k0+128 into buf0
    if (k0 + 128 < 1024) {
      stage64(A, sA, Bt, sB, m0, n0, k0 + 128, la0, lb0, wave, rg, colo);
      asm volatile("s_waitcnt vmcnt(8)" ::: "memory");
    } else {
      asm volatile("s_waitcnt vmcnt(0)" ::: "memory");
    }
    bar();
    compute64(la1, lb1, acc, wm, wn, quad, l16);
    bar();
  }
}

__device__ __forceinline__ void zero_acc(f32x4 acc[4][4]) {
#pragma unroll
  for (int i = 0; i < 4; ++i)
#pragma unroll
    for (int j = 0; j < 4; ++j)
#pragma unroll
      for (int r = 0; r < 4; ++r) acc[i][j][r] = 0.0f;
}

// ---------------- GEMM1: Sup2[d][b*1024+n] = (y@W)^T ----------------

__global__ __launch_bounds__(256) void k_gemm1(
    const unsigned short* __restrict__ Wt,    // [1024][1024]
    const unsigned short* __restrict__ Ybf,   // [8192][1024]
    unsigned short* __restrict__ Sup2)        // [1024][8192]
{
  __shared__ __align__(16) unsigned short lsm[4 * 8192];
  const int tid = threadIdx.x;
  const int n0 = blockIdx.x * 128, m0 = blockIdx.y * 128;

  f32x4 acc[4][4];
  zero_acc(acc);
  gemm_dbuf(Wt, 1024, Ybf, 1024, m0, n0, acc, lsm, tid);

  const int lane = tid & 63, wave = tid >> 6;
  const int wm = (wave >> 1) * 64, wn = (wave & 1) * 64;
  const int quad = lane >> 4, l16 = lane & 15;
#pragma unroll
  for (int i = 0; i < 4; ++i) {
    const int mb = m0 + wm + i * 16 + quad * 4;
#pragma unroll
    for (int r = 0; r < 4; ++r) {
      unsigned short* row = Sup2 + ((size_t)(mb + r) << 13);
#pragma unroll
      for (int j = 0; j < 4; ++j)
        row[n0 + wn + j * 16 + l16] = f2bf(acc[i][j][r]);
    }
  }
}

// ------- GEMM2: out = relu(adj@support / rowsum + bias + x) -------

__global__ __launch_bounds__(256) void k_gemm2(
    const unsigned short* __restrict__ AdjBf, // [8][1024][1024]
    const unsigned short* __restrict__ Sup2,  // [1024][8192]
    const float* __restrict__ x,
    const float* __restrict__ sumrow,         // [8][1024]
    const float* __restrict__ bias,           // [1024]
    float* __restrict__ out)
{
  __shared__ __align__(16) unsigned short lsm[4 * 8192];
  const int tid = threadIdx.x;
  const int n0 = blockIdx.x * 128, m0 = blockIdx.y * 128, b = blockIdx.z;

  f32x4 acc[4][4];
  zero_acc(acc);
  gemm_dbuf(AdjBf + ((size_t)b << 20), 1024,
            Sup2 + ((size_t)b << 10), 8192,
            m0, n0, acc, lsm, tid);

  const float* xb = x   + ((size_t)b << 20);
  float*       ob = out + ((size_t)b << 20);
  const float* sr = sumrow + ((size_t)b << 10);
  const int lane = tid & 63, wave = tid >> 6;
  const int wm = (wave >> 1) * 64, wn = (wave & 1) * 64;
  const int quad = lane >> 4, l16 = lane & 15;

  float bv[4];
#pragma unroll
  for (int j = 0; j < 4; ++j) bv[j] = bias[n0 + wn + j * 16 + l16];

#pragma unroll
  for (int i = 0; i < 4; ++i) {
    const int mb = m0 + wm + i * 16 + quad * 4;
#pragma unroll
    for (int r = 0; r < 4; ++r) {
      const int m = mb + r;
      const float inv = 1.0f / sr[m];
#pragma unroll
      for (int j = 0; j < 4; ++j) {
        const int n = n0 + wn + j * 16 + l16;
        const size_t idx = (((size_t)m) << 10) + n;
        float v = acc[i][j][r] * inv + bv[j] + xb[idx];
        ob[idx] = fmaxf(v, 0.0f);
      }
    }
  }
}

// ---------------- launcher ----------------

extern "C" void kernel_launch(void* const* d_in, const int* in_sizes, int n_in,
                              void* d_out, int out_size, void* d_ws, size_t ws_size,
                              hipStream_t stream) {
  const float* x      = (const float*)d_in[0];
  const float* y      = (const float*)d_in[1];
  const float* adj    = (const float*)d_in[2];
  const float* sumrow = (const float*)d_in[3];
  const float* W      = (const float*)d_in[4];
  const float* bias   = (const float*)d_in[5];
  float* out = (float*)d_out;

  char* ws = (char*)d_ws;
  unsigned short* ybf   = (unsigned short*)(ws);                       // 16 MB
  unsigned short* adjbf = (unsigned short*)(ws + ((size_t)16 << 20));  // 16 MB
  unsigned short* wt    = (unsigned short*)(ws + ((size_t)32 << 20));  //  2 MB
  unsigned short* sup2  = (unsigned short*)(ws + ((size_t)34 << 20));  // 16 MB

  k_prep<<<dim3(16640), dim3(256), 0, stream>>>(
      (const float4*)y, (const float4*)adj, (ushort4*)ybf, (ushort4*)adjbf, W, wt);
  k_gemm1<<<dim3(64, 8), dim3(256), 0, stream>>>(wt, ybf, sup2);
  k_gemm2<<<dim3(8, 8, 8), dim3(256), 0, stream>>>(adjbf, sup2, x, sumrow, bias, out);
}